// Round 1
// baseline (1121.400 us; speedup 1.0000x reference)
//
#include <hip/hip_runtime.h>

#define N_NODES 50000
#define N_EDGES 1600000
#define HD 64   // H*D
#define NH 8    // heads

// ---------------------------------------------------------------- CSR build
__global__ __launch_bounds__(256) void count_kernel(const int* __restrict__ dst,
                                                    int* __restrict__ cnt) {
    int e = blockIdx.x * 256 + threadIdx.x;
    if (e < N_EDGES) atomicAdd(&cnt[dst[e]], 1);
}

__global__ __launch_bounds__(1024) void scan_kernel(const int* __restrict__ cnt,
                                                    int* __restrict__ rowptr,
                                                    int* __restrict__ cursor) {
    __shared__ int tmp[1024];
    __shared__ int carry_s;
    int t = threadIdx.x;
    if (t == 0) carry_s = 0;
    __syncthreads();
    for (int base = 0; base < N_NODES; base += 1024) {
        int i = base + t;
        int v = (i < N_NODES) ? cnt[i] : 0;
        tmp[t] = v;
        __syncthreads();
        int acc = v;
        for (int off = 1; off < 1024; off <<= 1) {
            int add = (t >= off) ? tmp[t - off] : 0;
            __syncthreads();
            acc += add;
            tmp[t] = acc;
            __syncthreads();
        }
        int excl = acc - v;
        int carry = carry_s;
        if (i < N_NODES) { rowptr[i] = carry + excl; cursor[i] = carry + excl; }
        __syncthreads();
        if (t == 1023) carry_s = carry + acc;
        __syncthreads();
    }
    if (t == 0) rowptr[N_NODES] = carry_s;
}

__global__ __launch_bounds__(256) void fill_kernel(const int* __restrict__ src,
                                                   const int* __restrict__ dst,
                                                   int* __restrict__ cursor,
                                                   int* __restrict__ csr_src) {
    int e = blockIdx.x * 256 + threadIdx.x;
    if (e < N_EDGES) {
        int d = dst[e];
        int pos = atomicAdd(&cursor[d], 1);
        csr_src[pos] = src[e];
    }
}

// ------------------------------------------------- GEMM + attention logits
// h = x @ W  [N, 64]; e_src[n,hd] = sum_d h[n,hd,d]*att[0,hd,d]; same for e_dst.
// Wave = 4 nodes, lane = output feature (head*8+d). W staged transposed in LDS
// (stride F+4: 16B-aligned, bank-rotated). 1 W b128 + 4 x-broadcast b128 per 16 FMA.
template <int F>
__global__ __launch_bounds__(256) void gemm_att_kernel(
    const float* __restrict__ x, const float* __restrict__ W,
    const float* __restrict__ att,
    float* __restrict__ h, float* __restrict__ es, float* __restrict__ ed) {
    constexpr int FP = F + 4;
    __shared__ float Wt[64 * FP];
    __shared__ float xr[16 * F];
    int t = threadIdx.x;
    // stage W transposed: Wt[f*FP + k] = W[k*64 + f]
    for (int i = t; i < F * 64; i += 256) {
        int k = i >> 6, f = i & 63;
        Wt[f * FP + k] = W[i];
    }
    int wave = t >> 6, lane = t & 63;
    int node0 = blockIdx.x * 16 + wave * 4;
    // stage 4 x-rows per wave
    for (int r = 0; r < 4; r++) {
        int n = node0 + r;
        if (n < N_NODES)
            for (int k = lane; k < F; k += 64) xr[(wave * 4 + r) * F + k] = x[n * F + k];
    }
    __syncthreads();

    float acc0 = 0.f, acc1 = 0.f, acc2 = 0.f, acc3 = 0.f;
    const float4* w4p = (const float4*)&Wt[lane * FP];
    const float4* x0p = (const float4*)&xr[(wave * 4 + 0) * F];
    const float4* x1p = (const float4*)&xr[(wave * 4 + 1) * F];
    const float4* x2p = (const float4*)&xr[(wave * 4 + 2) * F];
    const float4* x3p = (const float4*)&xr[(wave * 4 + 3) * F];
#pragma unroll 4
    for (int kk = 0; kk < F / 4; kk++) {
        float4 w4 = w4p[kk];
        float4 v;
        v = x0p[kk]; acc0 += w4.x * v.x + w4.y * v.y + w4.z * v.z + w4.w * v.w;
        v = x1p[kk]; acc1 += w4.x * v.x + w4.y * v.y + w4.z * v.z + w4.w * v.w;
        v = x2p[kk]; acc2 += w4.x * v.x + w4.y * v.y + w4.z * v.z + w4.w * v.w;
        v = x3p[kk]; acc3 += w4.x * v.x + w4.y * v.y + w4.z * v.z + w4.w * v.w;
    }

    float a0 = att[lane];        // att[0][head][d], lane == head*8+d
    float a1 = att[64 + lane];   // att[1][head][d]
    float accs[4] = {acc0, acc1, acc2, acc3};
#pragma unroll
    for (int r = 0; r < 4; r++) {
        int n = node0 + r;
        float v = accs[r];
        float p0 = v * a0, p1 = v * a1;
        p0 += __shfl_xor(p0, 1); p0 += __shfl_xor(p0, 2); p0 += __shfl_xor(p0, 4);
        p1 += __shfl_xor(p1, 1); p1 += __shfl_xor(p1, 2); p1 += __shfl_xor(p1, 4);
        if (n < N_NODES) {
            h[n * HD + lane] = v;
            if ((lane & 7) == 0) {
                es[n * NH + (lane >> 3)] = p0;
                ed[n * NH + (lane >> 3)] = p1;
            }
        }
    }
}

// ------------------------------------------------------------- aggregation
// One wave per dst node; lane = output feature (head*8+d). Single pass:
// out = (sum_j w_j * h[src_j]) / (sum_j w_j + 1e-16) + b, w_j = exp(lrelu(...)).
// No max subtraction (alpha is shift-invariant; logits are O(1)). Fused bias+ELU.
__global__ __launch_bounds__(256) void agg_kernel(
    const float* __restrict__ h, const float* __restrict__ es,
    const float* __restrict__ ed, const int* __restrict__ rowptr,
    const int* __restrict__ csr_src, const float* __restrict__ b,
    float* __restrict__ out, int apply_elu) {
    int wave = threadIdx.x >> 6, lane = threadIdx.x & 63;
    int n = blockIdx.x * 4 + wave;
    if (n >= N_NODES) return;
    int head = lane >> 3;
    int beg = rowptr[n], end = rowptr[n + 1];
    float edn = ed[n * NH + head];
    float acc = 0.f, ssum = 0.f;
    for (int j = beg; j < end; j++) {
        int s = csr_src[j];
        float hv = h[s * HD + lane];
        float e = es[s * NH + head] + edn;
        e = (e > 0.f) ? e : 0.2f * e;
        float w = __expf(e);
        acc += w * hv;
        ssum += w;
    }
    float o = acc / (ssum + 1e-16f) + b[lane];
    if (apply_elu) o = (o > 0.f) ? o : (__expf(o) - 1.f);
    out[n * HD + lane] = o;
}

// ---------------------------------------------------------------- launcher
extern "C" void kernel_launch(void* const* d_in, const int* in_sizes, int n_in,
                              void* d_out, int out_size, void* d_ws, size_t ws_size,
                              hipStream_t stream) {
    const float* x   = (const float*)d_in[0];
    const int*   ei  = (const int*)d_in[1];
    const int*   src = ei;
    const int*   dst = ei + N_EDGES;
    const float* W[4]   = {(const float*)d_in[2], (const float*)d_in[5],
                           (const float*)d_in[8], (const float*)d_in[11]};
    const float* att[4] = {(const float*)d_in[3], (const float*)d_in[6],
                           (const float*)d_in[9], (const float*)d_in[12]};
    const float* bb[4]  = {(const float*)d_in[4], (const float*)d_in[7],
                           (const float*)d_in[10], (const float*)d_in[13]};

    char* wsb = (char*)d_ws;
    size_t off = 0;
    auto alloc = [&](size_t bytes) -> void* {
        size_t a = (off + 255) & ~(size_t)255;
        off = a + bytes;
        return (void*)(wsb + a);
    };
    int*   cnt    = (int*)alloc((size_t)N_NODES * 4);
    int*   cursor = (int*)alloc((size_t)N_NODES * 4);
    int*   rowptr = (int*)alloc((size_t)(N_NODES + 1) * 4);
    int*   csr    = (int*)alloc((size_t)N_EDGES * 4);
    float* h      = (float*)alloc((size_t)N_NODES * HD * 4);
    float* es     = (float*)alloc((size_t)N_NODES * NH * 4);
    float* ed     = (float*)alloc((size_t)N_NODES * NH * 4);
    float* act0   = (float*)alloc((size_t)N_NODES * HD * 4);
    float* act1   = (float*)alloc((size_t)N_NODES * HD * 4);

    // CSR build (graph is identical every call; rebuilt every call — no guards)
    hipMemsetAsync(cnt, 0, (size_t)N_NODES * 4, stream);
    count_kernel<<<N_EDGES / 256, 256, 0, stream>>>(dst, cnt);
    scan_kernel<<<1, 1024, 0, stream>>>(cnt, rowptr, cursor);
    fill_kernel<<<N_EDGES / 256, 256, 0, stream>>>(src, dst, cursor, csr);

    const int GG = N_NODES / 16;  // 3125, exact
    const int GA = N_NODES / 4;   // 12500, exact

    // layer 0 (F=128)
    gemm_att_kernel<128><<<GG, 256, 0, stream>>>(x, W[0], att[0], h, es, ed);
    agg_kernel<<<GA, 256, 0, stream>>>(h, es, ed, rowptr, csr, bb[0], act0, 1);
    // layer 1
    gemm_att_kernel<64><<<GG, 256, 0, stream>>>(act0, W[1], att[1], h, es, ed);
    agg_kernel<<<GA, 256, 0, stream>>>(h, es, ed, rowptr, csr, bb[1], act1, 1);
    // layer 2
    gemm_att_kernel<64><<<GG, 256, 0, stream>>>(act1, W[2], att[2], h, es, ed);
    agg_kernel<<<GA, 256, 0, stream>>>(h, es, ed, rowptr, csr, bb[2], act0, 1);
    // layer 3 (no ELU, write d_out)
    gemm_att_kernel<64><<<GG, 256, 0, stream>>>(act0, W[3], att[3], h, es, ed);
    agg_kernel<<<GA, 256, 0, stream>>>(h, es, ed, rowptr, csr, bb[3],
                                       (float*)d_out, 0);
}

// Round 2
// 654.840 us; speedup vs baseline: 1.7125x; 1.7125x over previous
//
#include <hip/hip_runtime.h>

#define N_NODES 50000
#define N_EDGES 1600000
#define HD 64   // H*D
#define NH 8    // heads
#define NB 196  // scan blocks = ceil(50000/256)

// ---------------------------------------------------------------- CSR build
__global__ __launch_bounds__(256) void count_kernel(const int* __restrict__ dst,
                                                    int* __restrict__ cnt) {
    int e = blockIdx.x * 256 + threadIdx.x;
    if (e < N_EDGES) atomicAdd(&cnt[dst[e]], 1);
}

__device__ inline int wave_incl_scan(int v, int lane) {
#pragma unroll
    for (int o = 1; o < 64; o <<= 1) {
        int t = __shfl_up(v, o);
        if (lane >= o) v += t;
    }
    return v;
}

// block-local exclusive scan; rowptr[i] = local excl, part[b] = block total
__global__ __launch_bounds__(256) void scanA_kernel(const int* __restrict__ cnt,
                                                    int* __restrict__ rowptr,
                                                    int* __restrict__ part) {
    int t = threadIdx.x;
    int i = blockIdx.x * 256 + t;
    int lane = t & 63, wv = t >> 6;
    int v = (i < N_NODES) ? cnt[i] : 0;
    int inc = wave_incl_scan(v, lane);
    __shared__ int wsum[4];
    if (lane == 63) wsum[wv] = inc;
    __syncthreads();
    if (t == 0) {
        int a = 0;
        for (int k = 0; k < 4; k++) { int s = wsum[k]; wsum[k] = a; a += s; }
    }
    __syncthreads();
    int excl = wsum[wv] + inc - v;
    if (i < N_NODES) rowptr[i] = excl;
    if (t == 255) part[blockIdx.x] = wsum[wv] + inc;
}

// scan the NB partials in place; write grand total to rowptr[N_NODES]
__global__ __launch_bounds__(256) void scanB_kernel(int* __restrict__ part,
                                                    int* __restrict__ rowptr) {
    int t = threadIdx.x;
    int lane = t & 63, wv = t >> 6;
    int v = (t < NB) ? part[t] : 0;
    int inc = wave_incl_scan(v, lane);
    __shared__ int wsum[4];
    if (lane == 63) wsum[wv] = inc;
    __syncthreads();
    if (t == 0) {
        int a = 0;
        for (int k = 0; k < 4; k++) { int s = wsum[k]; wsum[k] = a; a += s; }
    }
    __syncthreads();
    int excl = wsum[wv] + inc - v;
    if (t < NB) part[t] = excl;
    if (t == NB - 1) rowptr[N_NODES] = excl + v;
}

// add block offsets; init cursor
__global__ __launch_bounds__(256) void scanC_kernel(const int* __restrict__ part,
                                                    int* __restrict__ rowptr,
                                                    int* __restrict__ cursor) {
    int i = blockIdx.x * 256 + threadIdx.x;
    if (i < N_NODES) {
        int r = rowptr[i] + part[blockIdx.x];
        rowptr[i] = r;
        cursor[i] = r;
    }
}

__global__ __launch_bounds__(256) void fill_kernel(const int* __restrict__ src,
                                                   const int* __restrict__ dst,
                                                   int* __restrict__ cursor,
                                                   int* __restrict__ csr_src) {
    int e = blockIdx.x * 256 + threadIdx.x;
    if (e < N_EDGES) {
        int d = dst[e];
        int pos = atomicAdd(&cursor[d], 1);
        csr_src[pos] = src[e];
    }
}

// ------------------------------------------------- GEMM + attention logits
template <int F>
__global__ __launch_bounds__(256) void gemm_att_kernel(
    const float* __restrict__ x, const float* __restrict__ W,
    const float* __restrict__ att,
    float* __restrict__ h, float* __restrict__ es, float* __restrict__ ed) {
    constexpr int FP = F + 4;
    __shared__ float Wt[64 * FP];
    __shared__ float xr[16 * F];
    int t = threadIdx.x;
    for (int i = t; i < F * 64; i += 256) {
        int k = i >> 6, f = i & 63;
        Wt[f * FP + k] = W[i];
    }
    int wave = t >> 6, lane = t & 63;
    int node0 = blockIdx.x * 16 + wave * 4;
    for (int r = 0; r < 4; r++) {
        int n = node0 + r;
        if (n < N_NODES)
            for (int k = lane; k < F; k += 64) xr[(wave * 4 + r) * F + k] = x[n * F + k];
    }
    __syncthreads();

    float acc0 = 0.f, acc1 = 0.f, acc2 = 0.f, acc3 = 0.f;
    const float4* w4p = (const float4*)&Wt[lane * FP];
    const float4* x0p = (const float4*)&xr[(wave * 4 + 0) * F];
    const float4* x1p = (const float4*)&xr[(wave * 4 + 1) * F];
    const float4* x2p = (const float4*)&xr[(wave * 4 + 2) * F];
    const float4* x3p = (const float4*)&xr[(wave * 4 + 3) * F];
#pragma unroll 4
    for (int kk = 0; kk < F / 4; kk++) {
        float4 w4 = w4p[kk];
        float4 v;
        v = x0p[kk]; acc0 += w4.x * v.x + w4.y * v.y + w4.z * v.z + w4.w * v.w;
        v = x1p[kk]; acc1 += w4.x * v.x + w4.y * v.y + w4.z * v.z + w4.w * v.w;
        v = x2p[kk]; acc2 += w4.x * v.x + w4.y * v.y + w4.z * v.z + w4.w * v.w;
        v = x3p[kk]; acc3 += w4.x * v.x + w4.y * v.y + w4.z * v.z + w4.w * v.w;
    }

    float a0 = att[lane];
    float a1 = att[64 + lane];
    float accs[4] = {acc0, acc1, acc2, acc3};
#pragma unroll
    for (int r = 0; r < 4; r++) {
        int n = node0 + r;
        float v = accs[r];
        float p0 = v * a0, p1 = v * a1;
        p0 += __shfl_xor(p0, 1); p0 += __shfl_xor(p0, 2); p0 += __shfl_xor(p0, 4);
        p1 += __shfl_xor(p1, 1); p1 += __shfl_xor(p1, 2); p1 += __shfl_xor(p1, 4);
        if (n < N_NODES) {
            h[n * HD + lane] = v;
            if ((lane & 7) == 0) {
                es[n * NH + (lane >> 3)] = p0;
                ed[n * NH + (lane >> 3)] = p1;
            }
        }
    }
}

// ------------------------------------------------------------- aggregation
// Wave per dst node. Lane L: group g=L>>4 handles one edge per batch; q=L&15
// is the feature quad (features 4q..4q+3, head q>>1). 4 edges/batch, unroll 2
// -> 8 independent h-row chains in flight. Cross-group combine via shfl_xor.
__global__ __launch_bounds__(256) void agg_kernel(
    const float4* __restrict__ h4, const float* __restrict__ es,
    const float* __restrict__ ed, const int* __restrict__ rowptr,
    const int* __restrict__ csr, const float4* __restrict__ b4,
    float4* __restrict__ out4, int apply_elu) {
    int t = threadIdx.x;
    int wv = t >> 6, L = t & 63;
    int n = blockIdx.x * 4 + wv;
    if (n >= N_NODES) return;
    int g = L >> 4, q = L & 15, head = q >> 1;
    int beg = rowptr[n], end = rowptr[n + 1];
    float edn = ed[n * NH + head];
    float4 acc = {0.f, 0.f, 0.f, 0.f};
    float ssum = 0.f;
    int j = beg;
    for (; j + 8 <= end; j += 8) {
        int s0 = csr[j + g];
        int s1 = csr[j + 4 + g];
        float4 hv0 = h4[s0 * 16 + q];
        float4 hv1 = h4[s1 * 16 + q];
        float e0 = es[s0 * NH + head] + edn;
        float e1 = es[s1 * NH + head] + edn;
        e0 = (e0 > 0.f) ? e0 : 0.2f * e0;
        e1 = (e1 > 0.f) ? e1 : 0.2f * e1;
        float w0 = __expf(e0), w1 = __expf(e1);
        acc.x += w0 * hv0.x; acc.y += w0 * hv0.y; acc.z += w0 * hv0.z; acc.w += w0 * hv0.w;
        acc.x += w1 * hv1.x; acc.y += w1 * hv1.y; acc.z += w1 * hv1.z; acc.w += w1 * hv1.w;
        ssum += w0 + w1;
    }
    for (; j + 4 <= end; j += 4) {
        int s0 = csr[j + g];
        float4 hv0 = h4[s0 * 16 + q];
        float e0 = es[s0 * NH + head] + edn;
        e0 = (e0 > 0.f) ? e0 : 0.2f * e0;
        float w0 = __expf(e0);
        acc.x += w0 * hv0.x; acc.y += w0 * hv0.y; acc.z += w0 * hv0.z; acc.w += w0 * hv0.w;
        ssum += w0;
    }
    int rem = end - j;
    if (rem > 0) {
        float w0 = 0.f;
        float4 hv0 = {0.f, 0.f, 0.f, 0.f};
        if (g < rem) {
            int s0 = csr[j + g];
            hv0 = h4[s0 * 16 + q];
            float e0 = es[s0 * NH + head] + edn;
            e0 = (e0 > 0.f) ? e0 : 0.2f * e0;
            w0 = __expf(e0);
        }
        acc.x += w0 * hv0.x; acc.y += w0 * hv0.y; acc.z += w0 * hv0.z; acc.w += w0 * hv0.w;
        ssum += w0;
    }
    // combine the 4 edge-groups (lanes L, L^16, L^32, L^48)
    acc.x += __shfl_xor(acc.x, 16); acc.x += __shfl_xor(acc.x, 32);
    acc.y += __shfl_xor(acc.y, 16); acc.y += __shfl_xor(acc.y, 32);
    acc.z += __shfl_xor(acc.z, 16); acc.z += __shfl_xor(acc.z, 32);
    acc.w += __shfl_xor(acc.w, 16); acc.w += __shfl_xor(acc.w, 32);
    ssum  += __shfl_xor(ssum, 16);  ssum  += __shfl_xor(ssum, 32);

    float inv = 1.f / (ssum + 1e-16f);
    float4 bv = b4[q];
    float4 o;
    o.x = acc.x * inv + bv.x;
    o.y = acc.y * inv + bv.y;
    o.z = acc.z * inv + bv.z;
    o.w = acc.w * inv + bv.w;
    if (apply_elu) {
        o.x = (o.x > 0.f) ? o.x : (__expf(o.x) - 1.f);
        o.y = (o.y > 0.f) ? o.y : (__expf(o.y) - 1.f);
        o.z = (o.z > 0.f) ? o.z : (__expf(o.z) - 1.f);
        o.w = (o.w > 0.f) ? o.w : (__expf(o.w) - 1.f);
    }
    if (g == 0) out4[n * 16 + q] = o;
}

// ---------------------------------------------------------------- launcher
extern "C" void kernel_launch(void* const* d_in, const int* in_sizes, int n_in,
                              void* d_out, int out_size, void* d_ws, size_t ws_size,
                              hipStream_t stream) {
    const float* x   = (const float*)d_in[0];
    const int*   ei  = (const int*)d_in[1];
    const int*   src = ei;
    const int*   dst = ei + N_EDGES;
    const float* W[4]   = {(const float*)d_in[2], (const float*)d_in[5],
                           (const float*)d_in[8], (const float*)d_in[11]};
    const float* att[4] = {(const float*)d_in[3], (const float*)d_in[6],
                           (const float*)d_in[9], (const float*)d_in[12]};
    const float* bb[4]  = {(const float*)d_in[4], (const float*)d_in[7],
                           (const float*)d_in[10], (const float*)d_in[13]};

    char* wsb = (char*)d_ws;
    size_t off = 0;
    auto alloc = [&](size_t bytes) -> void* {
        size_t a = (off + 255) & ~(size_t)255;
        off = a + bytes;
        return (void*)(wsb + a);
    };
    int*   cnt    = (int*)alloc((size_t)N_NODES * 4);
    int*   cursor = (int*)alloc((size_t)N_NODES * 4);
    int*   rowptr = (int*)alloc((size_t)(N_NODES + 1) * 4);
    int*   part   = (int*)alloc((size_t)NB * 4);
    int*   csr    = (int*)alloc((size_t)N_EDGES * 4);
    float* h      = (float*)alloc((size_t)N_NODES * HD * 4);
    float* es     = (float*)alloc((size_t)N_NODES * NH * 4);
    float* ed     = (float*)alloc((size_t)N_NODES * NH * 4);
    float* act0   = (float*)alloc((size_t)N_NODES * HD * 4);
    float* act1   = (float*)alloc((size_t)N_NODES * HD * 4);

    // CSR build
    hipMemsetAsync(cnt, 0, (size_t)N_NODES * 4, stream);
    count_kernel<<<N_EDGES / 256, 256, 0, stream>>>(dst, cnt);
    scanA_kernel<<<NB, 256, 0, stream>>>(cnt, rowptr, part);
    scanB_kernel<<<1, 256, 0, stream>>>(part, rowptr);
    scanC_kernel<<<NB, 256, 0, stream>>>(part, rowptr, cursor);
    fill_kernel<<<N_EDGES / 256, 256, 0, stream>>>(src, dst, cursor, csr);

    const int GG = N_NODES / 16;  // 3125
    const int GA = N_NODES / 4;   // 12500

    gemm_att_kernel<128><<<GG, 256, 0, stream>>>(x, W[0], att[0], h, es, ed);
    agg_kernel<<<GA, 256, 0, stream>>>((const float4*)h, es, ed, rowptr, csr,
                                       (const float4*)bb[0], (float4*)act0, 1);
    gemm_att_kernel<64><<<GG, 256, 0, stream>>>(act0, W[1], att[1], h, es, ed);
    agg_kernel<<<GA, 256, 0, stream>>>((const float4*)h, es, ed, rowptr, csr,
                                       (const float4*)bb[1], (float4*)act1, 1);
    gemm_att_kernel<64><<<GG, 256, 0, stream>>>(act1, W[2], att[2], h, es, ed);
    agg_kernel<<<GA, 256, 0, stream>>>((const float4*)h, es, ed, rowptr, csr,
                                       (const float4*)bb[2], (float4*)act0, 1);
    gemm_att_kernel<64><<<GG, 256, 0, stream>>>(act0, W[3], att[3], h, es, ed);
    agg_kernel<<<GA, 256, 0, stream>>>((const float4*)h, es, ed, rowptr, csr,
                                       (const float4*)bb[3], (float4*)d_out, 0);
}

// Round 3
// 451.010 us; speedup vs baseline: 2.4864x; 1.4519x over previous
//
#include <hip/hip_runtime.h>

#define N_NODES 50000
#define N_EDGES 1600000
#define HD 64   // H*D
#define NH 8    // heads
#define NB 196  // scan blocks = ceil(50000/256)

typedef __attribute__((ext_vector_type(4))) _Float16 half4;

// ---------------------------------------------------------------- CSR build
// count + per-edge rank in one pass (rank = return of the atomic we already pay)
__global__ __launch_bounds__(256) void count_kernel(const int* __restrict__ dst,
                                                    int* __restrict__ cnt,
                                                    int* __restrict__ rank) {
    int e = blockIdx.x * 256 + threadIdx.x;
    if (e < N_EDGES) rank[e] = atomicAdd(&cnt[dst[e]], 1);
}

__device__ inline int wave_incl_scan(int v, int lane) {
#pragma unroll
    for (int o = 1; o < 64; o <<= 1) {
        int t = __shfl_up(v, o);
        if (lane >= o) v += t;
    }
    return v;
}

__global__ __launch_bounds__(256) void scanA_kernel(const int* __restrict__ cnt,
                                                    int* __restrict__ rowptr,
                                                    int* __restrict__ part) {
    int t = threadIdx.x;
    int i = blockIdx.x * 256 + t;
    int lane = t & 63, wv = t >> 6;
    int v = (i < N_NODES) ? cnt[i] : 0;
    int inc = wave_incl_scan(v, lane);
    __shared__ int wsum[4];
    if (lane == 63) wsum[wv] = inc;
    __syncthreads();
    if (t == 0) {
        int a = 0;
        for (int k = 0; k < 4; k++) { int s = wsum[k]; wsum[k] = a; a += s; }
    }
    __syncthreads();
    int excl = wsum[wv] + inc - v;
    if (i < N_NODES) rowptr[i] = excl;
    if (t == 255) part[blockIdx.x] = wsum[wv] + inc;
}

__global__ __launch_bounds__(256) void scanB_kernel(int* __restrict__ part,
                                                    int* __restrict__ rowptr) {
    int t = threadIdx.x;
    int lane = t & 63, wv = t >> 6;
    int v = (t < NB) ? part[t] : 0;
    int inc = wave_incl_scan(v, lane);
    __shared__ int wsum[4];
    if (lane == 63) wsum[wv] = inc;
    __syncthreads();
    if (t == 0) {
        int a = 0;
        for (int k = 0; k < 4; k++) { int s = wsum[k]; wsum[k] = a; a += s; }
    }
    __syncthreads();
    int excl = wsum[wv] + inc - v;
    if (t < NB) part[t] = excl;
    if (t == NB - 1) rowptr[N_NODES] = excl + v;
}

__global__ __launch_bounds__(256) void scanC_kernel(const int* __restrict__ part,
                                                    int* __restrict__ rowptr) {
    int i = blockIdx.x * 256 + threadIdx.x;
    if (i < N_NODES) rowptr[i] += part[blockIdx.x];
}

// atomic-free fill: pos = rowptr[dst] + rank (diagnostic for store-bound theory)
__global__ __launch_bounds__(256) void fill_kernel(const int* __restrict__ src,
                                                   const int* __restrict__ dst,
                                                   const int* __restrict__ rank,
                                                   const int* __restrict__ rowptr,
                                                   int* __restrict__ csr_src) {
    int e = blockIdx.x * 256 + threadIdx.x;
    if (e < N_EDGES) {
        int pos = rowptr[dst[e]] + rank[e];
        csr_src[pos] = src[e];
    }
}

// ------------------------------------------------- GEMM + attention logits
// h stored fp16 (halves gather traffic in agg); es/ed stay fp32.
template <int F>
__global__ __launch_bounds__(256) void gemm_att_kernel(
    const float* __restrict__ x, const float* __restrict__ W,
    const float* __restrict__ att,
    _Float16* __restrict__ h, float* __restrict__ es, float* __restrict__ ed) {
    constexpr int FP = F + 4;
    __shared__ float Wt[64 * FP];
    __shared__ float xr[16 * F];
    int t = threadIdx.x;
    for (int i = t; i < F * 64; i += 256) {
        int k = i >> 6, f = i & 63;
        Wt[f * FP + k] = W[i];
    }
    int wave = t >> 6, lane = t & 63;
    int node0 = blockIdx.x * 16 + wave * 4;
    for (int r = 0; r < 4; r++) {
        int n = node0 + r;
        if (n < N_NODES)
            for (int k = lane; k < F; k += 64) xr[(wave * 4 + r) * F + k] = x[n * F + k];
    }
    __syncthreads();

    float acc0 = 0.f, acc1 = 0.f, acc2 = 0.f, acc3 = 0.f;
    const float4* w4p = (const float4*)&Wt[lane * FP];
    const float4* x0p = (const float4*)&xr[(wave * 4 + 0) * F];
    const float4* x1p = (const float4*)&xr[(wave * 4 + 1) * F];
    const float4* x2p = (const float4*)&xr[(wave * 4 + 2) * F];
    const float4* x3p = (const float4*)&xr[(wave * 4 + 3) * F];
#pragma unroll 4
    for (int kk = 0; kk < F / 4; kk++) {
        float4 w4 = w4p[kk];
        float4 v;
        v = x0p[kk]; acc0 += w4.x * v.x + w4.y * v.y + w4.z * v.z + w4.w * v.w;
        v = x1p[kk]; acc1 += w4.x * v.x + w4.y * v.y + w4.z * v.z + w4.w * v.w;
        v = x2p[kk]; acc2 += w4.x * v.x + w4.y * v.y + w4.z * v.z + w4.w * v.w;
        v = x3p[kk]; acc3 += w4.x * v.x + w4.y * v.y + w4.z * v.z + w4.w * v.w;
    }

    float a0 = att[lane];
    float a1 = att[64 + lane];
    float accs[4] = {acc0, acc1, acc2, acc3};
#pragma unroll
    for (int r = 0; r < 4; r++) {
        int n = node0 + r;
        float v = accs[r];
        float p0 = v * a0, p1 = v * a1;
        p0 += __shfl_xor(p0, 1); p0 += __shfl_xor(p0, 2); p0 += __shfl_xor(p0, 4);
        p1 += __shfl_xor(p1, 1); p1 += __shfl_xor(p1, 2); p1 += __shfl_xor(p1, 4);
        if (n < N_NODES) {
            h[n * HD + lane] = (_Float16)v;
            if ((lane & 7) == 0) {
                es[n * NH + (lane >> 3)] = p0;
                ed[n * NH + (lane >> 3)] = p1;
            }
        }
    }
}

// ------------------------------------------------------------- aggregation
// Wave per dst node. g=L>>4 edge subgroup, q=L&15 feature quad. h rows fp16
// (8B/lane/edge). 16-edge batches -> 4 independent gather chains per lane.
__device__ inline void edge_accum(const half4* __restrict__ h4,
                                  const float* __restrict__ es, float edn,
                                  int s, int q, int head,
                                  float4& acc, float& ssum) {
    half4 hv = h4[s * 16 + q];
    float e0 = es[s * NH + head] + edn;
    e0 = (e0 > 0.f) ? e0 : 0.2f * e0;
    float w0 = __expf(e0);
    acc.x += w0 * (float)hv.x; acc.y += w0 * (float)hv.y;
    acc.z += w0 * (float)hv.z; acc.w += w0 * (float)hv.w;
    ssum += w0;
}

__global__ __launch_bounds__(256) void agg_kernel(
    const half4* __restrict__ h4, const float* __restrict__ es,
    const float* __restrict__ ed, const int* __restrict__ rowptr,
    const int* __restrict__ csr, const float4* __restrict__ b4,
    float4* __restrict__ out4, int apply_elu) {
    int t = threadIdx.x;
    int wv = t >> 6, L = t & 63;
    int n = blockIdx.x * 4 + wv;
    if (n >= N_NODES) return;
    int g = L >> 4, q = L & 15, head = q >> 1;
    int beg = rowptr[n], end = rowptr[n + 1];
    float edn = ed[n * NH + head];
    float4 acc = {0.f, 0.f, 0.f, 0.f};
    float ssum = 0.f;
    int j = beg;
    for (; j + 16 <= end; j += 16) {
        int s0 = csr[j + g], s1 = csr[j + 4 + g];
        int s2 = csr[j + 8 + g], s3 = csr[j + 12 + g];
        edge_accum(h4, es, edn, s0, q, head, acc, ssum);
        edge_accum(h4, es, edn, s1, q, head, acc, ssum);
        edge_accum(h4, es, edn, s2, q, head, acc, ssum);
        edge_accum(h4, es, edn, s3, q, head, acc, ssum);
    }
    for (; j + 8 <= end; j += 8) {
        int s0 = csr[j + g], s1 = csr[j + 4 + g];
        edge_accum(h4, es, edn, s0, q, head, acc, ssum);
        edge_accum(h4, es, edn, s1, q, head, acc, ssum);
    }
    for (; j + 4 <= end; j += 4) {
        int s0 = csr[j + g];
        edge_accum(h4, es, edn, s0, q, head, acc, ssum);
    }
    int rem = end - j;
    if (rem > 0 && g < rem) {
        int s0 = csr[j + g];
        edge_accum(h4, es, edn, s0, q, head, acc, ssum);
    }
    acc.x += __shfl_xor(acc.x, 16); acc.x += __shfl_xor(acc.x, 32);
    acc.y += __shfl_xor(acc.y, 16); acc.y += __shfl_xor(acc.y, 32);
    acc.z += __shfl_xor(acc.z, 16); acc.z += __shfl_xor(acc.z, 32);
    acc.w += __shfl_xor(acc.w, 16); acc.w += __shfl_xor(acc.w, 32);
    ssum  += __shfl_xor(ssum, 16);  ssum  += __shfl_xor(ssum, 32);

    float inv = 1.f / (ssum + 1e-16f);
    float4 bv = b4[q];
    float4 o;
    o.x = acc.x * inv + bv.x;
    o.y = acc.y * inv + bv.y;
    o.z = acc.z * inv + bv.z;
    o.w = acc.w * inv + bv.w;
    if (apply_elu) {
        o.x = (o.x > 0.f) ? o.x : (__expf(o.x) - 1.f);
        o.y = (o.y > 0.f) ? o.y : (__expf(o.y) - 1.f);
        o.z = (o.z > 0.f) ? o.z : (__expf(o.z) - 1.f);
        o.w = (o.w > 0.f) ? o.w : (__expf(o.w) - 1.f);
    }
    if (g == 0) out4[n * 16 + q] = o;
}

// ---------------------------------------------------------------- launcher
extern "C" void kernel_launch(void* const* d_in, const int* in_sizes, int n_in,
                              void* d_out, int out_size, void* d_ws, size_t ws_size,
                              hipStream_t stream) {
    const float* x   = (const float*)d_in[0];
    const int*   ei  = (const int*)d_in[1];
    const int*   src = ei;
    const int*   dst = ei + N_EDGES;
    const float* W[4]   = {(const float*)d_in[2], (const float*)d_in[5],
                           (const float*)d_in[8], (const float*)d_in[11]};
    const float* att[4] = {(const float*)d_in[3], (const float*)d_in[6],
                           (const float*)d_in[9], (const float*)d_in[12]};
    const float* bb[4]  = {(const float*)d_in[4], (const float*)d_in[7],
                           (const float*)d_in[10], (const float*)d_in[13]};

    char* wsb = (char*)d_ws;
    size_t off = 0;
    auto alloc = [&](size_t bytes) -> void* {
        size_t a = (off + 255) & ~(size_t)255;
        off = a + bytes;
        return (void*)(wsb + a);
    };
    int*      cnt    = (int*)alloc((size_t)N_NODES * 4);
    int*      rowptr = (int*)alloc((size_t)(N_NODES + 1) * 4);
    int*      part   = (int*)alloc((size_t)NB * 4);
    int*      rank   = (int*)alloc((size_t)N_EDGES * 4);
    int*      csr    = (int*)alloc((size_t)N_EDGES * 4);
    _Float16* h      = (_Float16*)alloc((size_t)N_NODES * HD * 2);
    float*    es     = (float*)alloc((size_t)N_NODES * NH * 4);
    float*    ed     = (float*)alloc((size_t)N_NODES * NH * 4);
    float*    act0   = (float*)alloc((size_t)N_NODES * HD * 4);
    float*    act1   = (float*)alloc((size_t)N_NODES * HD * 4);

    hipMemsetAsync(cnt, 0, (size_t)N_NODES * 4, stream);
    count_kernel<<<N_EDGES / 256, 256, 0, stream>>>(dst, cnt, rank);
    scanA_kernel<<<NB, 256, 0, stream>>>(cnt, rowptr, part);
    scanB_kernel<<<1, 256, 0, stream>>>(part, rowptr);
    scanC_kernel<<<NB, 256, 0, stream>>>(part, rowptr);
    fill_kernel<<<N_EDGES / 256, 256, 0, stream>>>(src, dst, rank, rowptr, csr);

    const int GG = N_NODES / 16;  // 3125
    const int GA = N_NODES / 4;   // 12500

    gemm_att_kernel<128><<<GG, 256, 0, stream>>>(x, W[0], att[0], h, es, ed);
    agg_kernel<<<GA, 256, 0, stream>>>((const half4*)h, es, ed, rowptr, csr,
                                       (const float4*)bb[0], (float4*)act0, 1);
    gemm_att_kernel<64><<<GG, 256, 0, stream>>>(act0, W[1], att[1], h, es, ed);
    agg_kernel<<<GA, 256, 0, stream>>>((const half4*)h, es, ed, rowptr, csr,
                                       (const float4*)bb[1], (float4*)act1, 1);
    gemm_att_kernel<64><<<GG, 256, 0, stream>>>(act1, W[2], att[2], h, es, ed);
    agg_kernel<<<GA, 256, 0, stream>>>((const half4*)h, es, ed, rowptr, csr,
                                       (const float4*)bb[2], (float4*)act0, 1);
    gemm_att_kernel<64><<<GG, 256, 0, stream>>>(act0, W[3], att[3], h, es, ed);
    agg_kernel<<<GA, 256, 0, stream>>>((const half4*)h, es, ed, rowptr, csr,
                                       (const float4*)bb[3], (float4*)d_out, 0);
}